// Round 3
// baseline (313.235 us; speedup 1.0000x reference)
//
#include <hip/hip_runtime.h>

typedef __attribute__((ext_vector_type(4))) float f32x4;
typedef __attribute__((ext_vector_type(8))) short s16x8;

#define ADJ_N 8192

__device__ __forceinline__ unsigned short f2bf(float f) {
  unsigned u = __float_as_uint(f);
  u += 0x7FFFu + ((u >> 16) & 1u);
  return (unsigned short)(u >> 16);
}

// ---------------------------------------------------------------------------
// Build B0 = W0 (bf16) in MFMA-fragment layout [ks][cg][lane][8]:
// lane holds B[k=ks*32+8*(lane>>4)+j][col=cg*16+(lane&15)]
// ---------------------------------------------------------------------------
__global__ __launch_bounds__(256) void build_B0(
    const float* __restrict__ w0, const float* __restrict__ c0,
    unsigned short* __restrict__ Bsw) {
  const int t = blockIdx.x * 256 + threadIdx.x;   // 0..262143
  const int ks = t >> 9;
  const int cg = (t >> 6) & 7;
  const int lane = t & 63;
  const int kb = ks * 32 + ((lane >> 4) << 3);
  const int col = cg * 16 + (lane & 15);
  const int r = kb >> 13;
  const int m = kb & (ADJ_N - 1);
  const float a0 = c0[r * 2 + 0], a1 = c0[r * 2 + 1];
  union { unsigned short v[8]; s16x8 s; } out;
#pragma unroll
  for (int j = 0; j < 8; ++j) {
    const size_t idx = (size_t)(m + j) * 128 + col;
    const float f = a0 * w0[idx] + a1 * w0[(size_t)1048576 + idx];
    out.v[j] = f2bf(f);
  }
  ((s16x8*)Bsw)[t] = out.s;
}

// ---------------------------------------------------------------------------
// build_B1: sum the 8 k-split partials of out0, relu, apply W1, emit bf16
// fragments for gemm2; also accumulate column sums of out0 into frep[0:128].
// NT loads on p0 (read-once) to preserve adjB residency in L3.
// ---------------------------------------------------------------------------
__global__ __launch_bounds__(512) void build_B1(
    const float* __restrict__ p0, const float* __restrict__ w1,
    const float* __restrict__ c1, unsigned short* __restrict__ Bsw1,
    float* __restrict__ frep) {
  __shared__ __align__(16) float hs[32][128];       // 16 KB
  __shared__ __align__(16) float w1t[2][64 * 128];  // 64 KB, [r][p][o] swizzled
  __shared__ float red[512];
  const int tid = threadIdx.x;
  const int m0 = blockIdx.x * 32;

  float cs = 0.f;
  for (int i = tid; i < 32 * 128; i += 512) {
    const int ml = i >> 7, col = i & 127;
    const size_t base = (size_t)(m0 + ml) * 128 + col;
    float s = 0.f;
#pragma unroll
    for (int sp = 0; sp < 8; ++sp)
      s += __builtin_nontemporal_load(&p0[(size_t)sp * 1048576 + base]);
    cs += s;
    hs[ml][col] = fmaxf(s, 0.f);
  }
  const float ca[2][2] = {{c1[0], c1[1]}, {c1[2], c1[3]}};
  for (int i = tid; i < 2 * 64 * 128; i += 512) {
    const int rr = i >> 13;
    const int p = (i >> 7) & 63;
    const int o = i & 127;
    const float v = ca[rr][0] * w1[(size_t)o * 64 + p] + ca[rr][1] * w1[8192 + (size_t)o * 64 + p];
    const int ch = (o >> 2) ^ (p & 31);             // bank swizzle
    w1t[rr][p * 128 + ch * 4 + (o & 3)] = v;
  }
  red[tid] = cs;
  __syncthreads();
  if (tid < 128)
    atomicAdd(&frep[tid], red[tid] + red[tid + 128] + red[tid + 256] + red[tid + 384]);

  for (int idx = tid; idx < 4096; idx += 512) {
    const int p = idx & 63;
    const int ml = (idx >> 6) & 31;
    const int rr = idx >> 11;
    float s = 0.f;
#pragma unroll
    for (int ch = 0; ch < 32; ++ch) {
      const f32x4 hv = *(const f32x4*)&hs[ml][ch * 4];
      const f32x4 wv = *(const f32x4*)((const char*)&w1t[rr][0] +
                                       ((size_t)p * 32 + (ch ^ (p & 31))) * 16);
      s += hv[0] * wv[0] + hv[1] * wv[1] + hv[2] * wv[2] + hv[3] * wv[3];
    }
    const int k = rr * ADJ_N + m0 + ml;
    const int ks = k >> 5, kin = k & 31;
    const int lane = ((kin >> 3) << 4) | (p & 15);
    const int j = kin & 7;
    const int cg = p >> 4;
    Bsw1[(((size_t)ks * 4 + cg) * 64 + lane) * 8 + j] = f2bf(s);
  }
}

// ---------------------------------------------------------------------------
// gemm1: partial0[split][n][c] = sum_{k in split} adj[n][k] * W0frag[k][c]
// A fp32 -> NT load -> cvt_pk bf16 -> MFMA, AND the bf16 fragments are stored
// to adjB (256 MB, L3-resident) for gemm2. BM=64, 4 waves, wave-private A;
// B fragments double-buffered in LDS via global_load_lds.
// ---------------------------------------------------------------------------
__global__ __launch_bounds__(256, 4) void gemm1_adj(
    const float* __restrict__ adj, const unsigned short* __restrict__ Bfr,
    float* __restrict__ outp, unsigned short* __restrict__ adjB) {
  constexpr int BN = 128, CGS = 8, BK = 64, KRANGE = 2048, NSTEP = 32;
  __shared__ __align__(16) unsigned short Bsb[2][2 * CGS * 512];  // 32 KB

  const int bx = blockIdx.x;
  const int mblk = bx >> 3;
  const int split = bx & 7;   // pinned to XCD bx%8; B0 slice L2-resident
  const int n0 = mblk * 64;
  const int k0 = split * KRANGE;
  const int r = k0 >> 13;
  const int m0k = k0 & (ADJ_N - 1);

  const int tid = threadIdx.x;
  const int w = tid >> 6;
  const int lane = tid & 63;
  const int lhi = lane >> 4, llo = lane & 15;
  const int rowa = n0 + w * 16 + llo;

  const float* __restrict__ adjw =
      adj + ((size_t)r << 26) + (size_t)rowa * ADJ_N + m0k + lhi * 8;
  unsigned short* __restrict__ adjBw =
      adjB + ((size_t)r << 26) + (size_t)rowa * ADJ_N + m0k + lhi * 8;

  f32x4 acc[CGS];
#pragma unroll
  for (int b = 0; b < CGS; ++b) acc[b] = (f32x4){0.f, 0.f, 0.f, 0.f};

  auto loadA = [&](int step, f32x4 (&dst)[4]) {
#pragma unroll
    for (int kc = 0; kc < 2; ++kc)
#pragma unroll
      for (int h = 0; h < 2; ++h)
        dst[kc * 2 + h] = __builtin_nontemporal_load(
            (const f32x4*)(adjw + step * BK + kc * 32 + h * 4));
  };

  auto stageB = [&](int buf, int step) {
    const int ksb = (k0 >> 5) + step * 2;
    const unsigned short* g = Bfr + (size_t)ksb * CGS * 512 + w * (CGS / 2) * 512 + lane * 8;
#pragma unroll
    for (int i = 0; i < CGS / 2; ++i) {
      __builtin_amdgcn_global_load_lds(
          (const __attribute__((address_space(1))) void*)(g + i * 512),
          (__attribute__((address_space(3))) void*)((char*)&Bsb[buf][0] +
                                                    (w * (CGS / 2) + i) * 1024),
          16, 0, 0);
    }
  };

  auto compute = [&](int buf, f32x4 (&cur)[4], int s) {
#pragma unroll
    for (int kc = 0; kc < 2; ++kc) {
      union { unsigned u[4]; s16x8 v; } cv;
      asm("v_cvt_pk_bf16_f32 %0, %1, %2" : "=v"(cv.u[0]) : "v"(cur[kc * 2][0]), "v"(cur[kc * 2][1]));
      asm("v_cvt_pk_bf16_f32 %0, %1, %2" : "=v"(cv.u[1]) : "v"(cur[kc * 2][2]), "v"(cur[kc * 2][3]));
      asm("v_cvt_pk_bf16_f32 %0, %1, %2" : "=v"(cv.u[2]) : "v"(cur[kc * 2 + 1][0]), "v"(cur[kc * 2 + 1][1]));
      asm("v_cvt_pk_bf16_f32 %0, %1, %2" : "=v"(cv.u[3]) : "v"(cur[kc * 2 + 1][2]), "v"(cur[kc * 2 + 1][3]));
      *(s16x8*)(adjBw + s * BK + kc * 32) = cv.v;   // plain store: want L3
#pragma unroll
      for (int fc = 0; fc < CGS; ++fc) {
        const s16x8 b = *(const s16x8*)((const char*)&Bsb[buf][0] +
                                        (((kc * CGS + fc) * 64 + lane) << 4));
        acc[fc] = __builtin_amdgcn_mfma_f32_16x16x32_bf16(cv.v, b, acc[fc], 0, 0, 0);
      }
    }
  };

  f32x4 a0[4], a1[4];
  loadA(0, a0);
  stageB(0, 0);
  __syncthreads();

  for (int s2 = 0; s2 < NSTEP; s2 += 2) {
    stageB(1, s2 + 1);
    loadA(s2 + 1, a1);
    compute(0, a0, s2);
    __syncthreads();
    if (s2 + 2 < NSTEP) {
      stageB(0, s2 + 2);
      loadA(s2 + 2, a0);
    }
    compute(1, a1, s2 + 1);
    __syncthreads();
  }

  // epilogue: NT stores to this split's partial tile (read-once data).
  float* po = outp + ((size_t)split * ADJ_N + (size_t)n0) * BN;
#pragma unroll
  for (int fc = 0; fc < CGS; ++fc)
#pragma unroll
    for (int q = 0; q < 4; ++q)
      __builtin_nontemporal_store(
          acc[fc][q], &po[(size_t)(w * 16 + lhi * 4 + q) * BN + fc * 16 + llo]);
}

// ---------------------------------------------------------------------------
// gemm2: partial1[split][n][c] = sum_{k in split} adjB[n][k] * B1frag[k][c]
// A is bf16 fragments straight from adjB (L3-resident) -> MFMA, no cvt.
// ---------------------------------------------------------------------------
__global__ __launch_bounds__(256, 4) void gemm2_adj(
    const unsigned short* __restrict__ adjB, const unsigned short* __restrict__ Bfr,
    float* __restrict__ outp) {
  constexpr int BN = 64, CGS = 4, BK = 64, KRANGE = 2048, NSTEP = 32;
  __shared__ __align__(16) unsigned short Bsb[2][2 * CGS * 512];  // 16 KB

  const int bx = blockIdx.x;
  const int mblk = bx >> 3;
  const int split = bx & 7;
  const int n0 = mblk * 64;
  const int k0 = split * KRANGE;
  const int r = k0 >> 13;
  const int m0k = k0 & (ADJ_N - 1);

  const int tid = threadIdx.x;
  const int w = tid >> 6;
  const int lane = tid & 63;
  const int lhi = lane >> 4, llo = lane & 15;
  const int rowa = n0 + w * 16 + llo;

  const unsigned short* __restrict__ adjw =
      adjB + ((size_t)r << 26) + (size_t)rowa * ADJ_N + m0k + lhi * 8;

  f32x4 acc[CGS];
#pragma unroll
  for (int b = 0; b < CGS; ++b) acc[b] = (f32x4){0.f, 0.f, 0.f, 0.f};

  auto loadA = [&](int step, s16x8 (&dst)[2]) {
    dst[0] = *(const s16x8*)(adjw + step * BK);
    dst[1] = *(const s16x8*)(adjw + step * BK + 32);
  };

  auto stageB = [&](int buf, int step) {
    const int ksb = (k0 >> 5) + step * 2;
    const unsigned short* g = Bfr + (size_t)ksb * CGS * 512 + w * (CGS / 2) * 512 + lane * 8;
#pragma unroll
    for (int i = 0; i < CGS / 2; ++i) {
      __builtin_amdgcn_global_load_lds(
          (const __attribute__((address_space(1))) void*)(g + i * 512),
          (__attribute__((address_space(3))) void*)((char*)&Bsb[buf][0] +
                                                    (w * (CGS / 2) + i) * 1024),
          16, 0, 0);
    }
  };

  auto compute = [&](int buf, s16x8 (&cur)[2]) {
#pragma unroll
    for (int kc = 0; kc < 2; ++kc)
#pragma unroll
      for (int fc = 0; fc < CGS; ++fc) {
        const s16x8 b = *(const s16x8*)((const char*)&Bsb[buf][0] +
                                        (((kc * CGS + fc) * 64 + lane) << 4));
        acc[fc] = __builtin_amdgcn_mfma_f32_16x16x32_bf16(cur[kc], b, acc[fc], 0, 0, 0);
      }
  };

  s16x8 a0[2], a1[2];
  loadA(0, a0);
  stageB(0, 0);
  __syncthreads();

  for (int s2 = 0; s2 < NSTEP; s2 += 2) {
    stageB(1, s2 + 1);
    loadA(s2 + 1, a1);
    compute(0, a0);
    __syncthreads();
    if (s2 + 2 < NSTEP) {
      stageB(0, s2 + 2);
      loadA(s2 + 2, a0);
    }
    compute(1, a1);
    __syncthreads();
  }

  float* po = outp + ((size_t)split * ADJ_N + (size_t)n0) * BN;
#pragma unroll
  for (int fc = 0; fc < CGS; ++fc)
#pragma unroll
    for (int q = 0; q < 4; ++q)
      __builtin_nontemporal_store(
          acc[fc][q], &po[(size_t)(w * 16 + lhi * 4 + q) * BN + fc * 16 + llo]);
}

// ---------------------------------------------------------------------------
// reduce_out1: out1 = sum of 8 partials; also colsum -> frep[128:192].
// ---------------------------------------------------------------------------
__global__ __launch_bounds__(256) void reduce_out1(
    const float* __restrict__ p1, float* __restrict__ out1,
    float* __restrict__ frep) {
  __shared__ float red[256];
  const int t = threadIdx.x;
  const int col = t & 63, r0 = t >> 6;
  float cs = 0.f;
  for (int k = 0; k < 8; ++k) {
    const size_t row = (size_t)blockIdx.x * 32 + r0 * 8 + k;
    const size_t idx = row * 64 + col;
    float s = 0.f;
#pragma unroll
    for (int sp = 0; sp < 8; ++sp)
      s += __builtin_nontemporal_load(&p1[(size_t)sp * 524288 + idx]);
    out1[idx] = s;
    cs += s;
  }
  red[t] = cs;
  __syncthreads();
  if (t < 64)
    atomicAdd(&frep[128 + t], red[t] + red[t + 64] + red[t + 128] + red[t + 192]);
}

// ---------------------------------------------------------------------------
extern "C" void kernel_launch(void* const* d_in, const int* in_sizes, int n_in,
                              void* d_out, int out_size, void* d_ws, size_t ws_size,
                              hipStream_t stream) {
  const float* adj = (const float*)d_in[0];
  const float* bw0 = (const float*)d_in[1];
  const float* bc0 = (const float*)d_in[2];
  const float* bw1 = (const float*)d_in[3];
  const float* bc1 = (const float*)d_in[4];
  float* out = (float*)d_out;
  float* frep = out + (size_t)8192 * 64;

  char* ws = (char*)d_ws;
  float* p0 = (float*)ws;                                      // 32 MB
  float* p1 = (float*)(ws + (32u << 20));                      // 16 MB
  unsigned short* B0 = (unsigned short*)(ws + (48u << 20));    // 4 MB
  unsigned short* B1 = (unsigned short*)(ws + (52u << 20));    // 2 MB
  unsigned short* adjB = (unsigned short*)(ws + (64u << 20));  // 256 MB bf16 adj

  hipMemsetAsync(frep, 0, 192 * sizeof(float), stream);

  build_B0<<<1024, 256, 0, stream>>>(bw0, bc0, B0);
  gemm1_adj<<<1024, 256, 0, stream>>>(adj, B0, p0, adjB);
  build_B1<<<256, 512, 0, stream>>>(p0, bw1, bc1, B1, frep);
  gemm2_adj<<<1024, 256, 0, stream>>>(adjB, B1, p1);
  reduce_out1<<<256, 256, 0, stream>>>(p1, out, frep);
}

// Round 4
// 293.930 us; speedup vs baseline: 1.0657x; 1.0657x over previous
//
#include <hip/hip_runtime.h>

typedef __attribute__((ext_vector_type(4))) float f32x4;
typedef __attribute__((ext_vector_type(8))) short s16x8;

#define ADJ_N 8192

__device__ __forceinline__ unsigned short f2bf(float f) {
  unsigned u = __float_as_uint(f);
  u += 0x7FFFu + ((u >> 16) & 1u);
  return (unsigned short)(u >> 16);
}

// ---------------------------------------------------------------------------
// Build B0 = W0 (bf16) in MFMA-fragment layout [ks][cg][lane][8]:
// lane holds B[k=ks*32+8*(lane>>4)+j][col=cg*16+(lane&15)]
// ---------------------------------------------------------------------------
__global__ __launch_bounds__(256) void build_B0(
    const float* __restrict__ w0, const float* __restrict__ c0,
    unsigned short* __restrict__ Bsw) {
  const int t = blockIdx.x * 256 + threadIdx.x;   // 0..262143
  const int ks = t >> 9;
  const int cg = (t >> 6) & 7;
  const int lane = t & 63;
  const int kb = ks * 32 + ((lane >> 4) << 3);
  const int col = cg * 16 + (lane & 15);
  const int r = kb >> 13;
  const int m = kb & (ADJ_N - 1);
  const float a0 = c0[r * 2 + 0], a1 = c0[r * 2 + 1];
  union { unsigned short v[8]; s16x8 s; } out;
#pragma unroll
  for (int j = 0; j < 8; ++j) {
    const size_t idx = (size_t)(m + j) * 128 + col;
    const float f = a0 * w0[idx] + a1 * w0[(size_t)1048576 + idx];
    out.v[j] = f2bf(f);
  }
  ((s16x8*)Bsw)[t] = out.s;
}

// ---------------------------------------------------------------------------
// build_W1c: W1c[r][o][p] = c1[r,0]*w1[0,o,p] + c1[r,1]*w1[1,o,p], packed as
// bf16 MFMA B-fragments [r][ks2 0..3][cg 0..3][lane][8]. Also zeroes frep.
// ---------------------------------------------------------------------------
__global__ __launch_bounds__(256) void build_W1c(
    const float* __restrict__ w1, const float* __restrict__ c1,
    unsigned short* __restrict__ W1c, float* __restrict__ frep) {
  const int t = blockIdx.x * 256 + threadIdx.x;   // 0..2047
  if (t < 192) frep[t] = 0.f;
  if (t >= 2048) return;
  const int f = t >> 6;
  const int lane = t & 63;
  const int r = f >> 4;
  const int ks2 = (f >> 2) & 3;
  const int cg = f & 3;
  const float a0 = c1[r * 2 + 0], a1 = c1[r * 2 + 1];
  union { unsigned short v[8]; s16x8 s; } out;
#pragma unroll
  for (int j = 0; j < 8; ++j) {
    const int o = ks2 * 32 + ((lane >> 4) << 3) + j;
    const int p = cg * 16 + (lane & 15);
    out.v[j] = f2bf(a0 * w1[(size_t)o * 64 + p] + a1 * w1[8192 + (size_t)o * 64 + p]);
  }
  ((s16x8*)W1c)[t] = out.s;
}

// ---------------------------------------------------------------------------
// gemm1: partial0[split][n][c] = sum_{k in split} adj[n][k] * W0frag[k][c]
// Round-2 proven structure: BM=64, 4 waves, wave-private A (global->reg->cvt),
// B fragments double-buffered in LDS via global_load_lds. split pinned to XCD.
// ---------------------------------------------------------------------------
__global__ __launch_bounds__(256, 4) void gemm1_adj(
    const float* __restrict__ adj, const unsigned short* __restrict__ Bfr,
    float* __restrict__ outp) {
  constexpr int BN = 128, CGS = 8, BK = 64, KRANGE = 2048, NSTEP = 32;
  __shared__ __align__(16) unsigned short Bsb[2][2 * CGS * 512];  // 32 KB

  const int bx = blockIdx.x;
  const int mblk = bx >> 3;
  const int split = bx & 7;
  const int n0 = mblk * 64;
  const int k0 = split * KRANGE;
  const int r = k0 >> 13;
  const int m0k = k0 & (ADJ_N - 1);

  const int tid = threadIdx.x;
  const int w = tid >> 6;
  const int lane = tid & 63;
  const int lhi = lane >> 4, llo = lane & 15;
  const int rowa = n0 + w * 16 + llo;

  const float* __restrict__ adjw =
      adj + ((size_t)r << 26) + (size_t)rowa * ADJ_N + m0k + lhi * 8;

  f32x4 acc[CGS];
#pragma unroll
  for (int b = 0; b < CGS; ++b) acc[b] = (f32x4){0.f, 0.f, 0.f, 0.f};

  auto loadA = [&](int step, f32x4 (&dst)[4]) {
#pragma unroll
    for (int kc = 0; kc < 2; ++kc)
#pragma unroll
      for (int h = 0; h < 2; ++h)
        dst[kc * 2 + h] = *(const f32x4*)(adjw + step * BK + kc * 32 + h * 4);
  };

  auto stageB = [&](int buf, int step) {
    const int ksb = (k0 >> 5) + step * 2;
    const unsigned short* g = Bfr + (size_t)ksb * CGS * 512 + w * (CGS / 2) * 512 + lane * 8;
#pragma unroll
    for (int i = 0; i < CGS / 2; ++i) {
      __builtin_amdgcn_global_load_lds(
          (const __attribute__((address_space(1))) void*)(g + i * 512),
          (__attribute__((address_space(3))) void*)((char*)&Bsb[buf][0] +
                                                    (w * (CGS / 2) + i) * 1024),
          16, 0, 0);
    }
  };

  auto compute = [&](int buf, f32x4 (&cur)[4]) {
#pragma unroll
    for (int kc = 0; kc < 2; ++kc) {
      union { unsigned u[4]; s16x8 v; } cv;
      asm("v_cvt_pk_bf16_f32 %0, %1, %2" : "=v"(cv.u[0]) : "v"(cur[kc * 2][0]), "v"(cur[kc * 2][1]));
      asm("v_cvt_pk_bf16_f32 %0, %1, %2" : "=v"(cv.u[1]) : "v"(cur[kc * 2][2]), "v"(cur[kc * 2][3]));
      asm("v_cvt_pk_bf16_f32 %0, %1, %2" : "=v"(cv.u[2]) : "v"(cur[kc * 2 + 1][0]), "v"(cur[kc * 2 + 1][1]));
      asm("v_cvt_pk_bf16_f32 %0, %1, %2" : "=v"(cv.u[3]) : "v"(cur[kc * 2 + 1][2]), "v"(cur[kc * 2 + 1][3]));
#pragma unroll
      for (int fc = 0; fc < CGS; ++fc) {
        const s16x8 b = *(const s16x8*)((const char*)&Bsb[buf][0] +
                                        (((kc * CGS + fc) * 64 + lane) << 4));
        acc[fc] = __builtin_amdgcn_mfma_f32_16x16x32_bf16(cv.v, b, acc[fc], 0, 0, 0);
      }
    }
  };

  f32x4 a0[4], a1[4];
  loadA(0, a0);
  stageB(0, 0);
  __syncthreads();

  for (int s2 = 0; s2 < NSTEP; s2 += 2) {
    stageB(1, s2 + 1);
    loadA(s2 + 1, a1);
    compute(0, a0);
    __syncthreads();
    if (s2 + 2 < NSTEP) {
      stageB(0, s2 + 2);
      loadA(s2 + 2, a0);
    }
    compute(1, a1);
    __syncthreads();
  }

  float* po = outp + ((size_t)split * ADJ_N + (size_t)n0) * BN;
#pragma unroll
  for (int fc = 0; fc < CGS; ++fc)
#pragma unroll
    for (int q = 0; q < 4; ++q)
      po[(size_t)(w * 16 + lhi * 4 + q) * BN + fc * 16 + llo] = acc[fc][q];
}

// ---------------------------------------------------------------------------
// reduce_h: h = relu(sum of 8 p0 splits); colsum0 (pre-relu) -> frep[0:128].
// 1024 blocks x 256 threads, 8 rows each (4 blocks/CU).
// ---------------------------------------------------------------------------
__global__ __launch_bounds__(256) void reduce_h(
    const float* __restrict__ p0, float* __restrict__ h,
    float* __restrict__ frep) {
  __shared__ float red[256];
  const int t = threadIdx.x;
  const int col = t & 127, rg = t >> 7;
  const int n0 = blockIdx.x * 8;
  float cs = 0.f;
#pragma unroll
  for (int rr = 0; rr < 4; ++rr) {
    const size_t idx = (size_t)(n0 + rg * 4 + rr) * 128 + col;
    float s = 0.f;
#pragma unroll
    for (int sp = 0; sp < 8; ++sp) s += p0[(size_t)sp * 1048576 + idx];
    cs += s;
    h[idx] = fmaxf(s, 0.f);
  }
  red[t] = cs;
  __syncthreads();
  if (t < 128) atomicAdd(&frep[t], red[t] + red[t + 128]);
}

// ---------------------------------------------------------------------------
// build_B1_mfma: Hc[k=r*8192+m][p] = sum_o h[m][o]*W1c[r][o][p] via MFMA,
// scattered to gemm2's B-fragment layout. 256 blocks x 128 threads (2 waves),
// 32 rows per block (wave w owns rows w*16..w*16+15).
// ---------------------------------------------------------------------------
__global__ __launch_bounds__(128) void build_B1_mfma(
    const float* __restrict__ h, const unsigned short* __restrict__ W1c,
    unsigned short* __restrict__ Bsw1) {
  __shared__ __align__(16) float hs[32][132];         // padded: no bank conflict
  __shared__ __align__(16) unsigned short wfr[16384]; // 32 KB W1c fragments
  __shared__ __align__(16) float T[2][16 * 68];       // per-wave bounce tile
  const int tid = threadIdx.x;
  const int m0 = blockIdx.x * 32;

  // stage W1c fragments (linear: dest = uniform + lane*16B)
#pragma unroll
  for (int i = 0; i < 16; ++i) {
    __builtin_amdgcn_global_load_lds(
        (const __attribute__((address_space(1))) void*)(W1c + (size_t)(i * 128 + tid) * 8),
        (__attribute__((address_space(3))) void*)&wfr[(i * 128 + tid) * 8],
        16, 0, 0);
  }
  // load h tile 32x128
  const f32x4* hg = (const f32x4*)(h + (size_t)m0 * 128);
#pragma unroll
  for (int i = 0; i < 8; ++i) {
    const int v = i * 128 + tid;
    const f32x4 val = hg[v];
    *(f32x4*)&hs[v >> 5][(v & 31) * 4] = val;
  }
  __syncthreads();

  const int w = tid >> 6;
  const int lane = tid & 63;
  const int hi = lane >> 4, llo = lane & 15;
  const int row = w * 16 + llo;

  f32x4 acc[2][4];
#pragma unroll
  for (int r = 0; r < 2; ++r)
#pragma unroll
    for (int cg = 0; cg < 4; ++cg) acc[r][cg] = (f32x4){0.f, 0.f, 0.f, 0.f};

#pragma unroll
  for (int ks2 = 0; ks2 < 4; ++ks2) {
    const f32x4 lo = *(const f32x4*)&hs[row][ks2 * 32 + hi * 8];
    const f32x4 hi4 = *(const f32x4*)&hs[row][ks2 * 32 + hi * 8 + 4];
    union { unsigned u[4]; s16x8 v; } cv;
    asm("v_cvt_pk_bf16_f32 %0, %1, %2" : "=v"(cv.u[0]) : "v"(lo[0]), "v"(lo[1]));
    asm("v_cvt_pk_bf16_f32 %0, %1, %2" : "=v"(cv.u[1]) : "v"(lo[2]), "v"(lo[3]));
    asm("v_cvt_pk_bf16_f32 %0, %1, %2" : "=v"(cv.u[2]) : "v"(hi4[0]), "v"(hi4[1]));
    asm("v_cvt_pk_bf16_f32 %0, %1, %2" : "=v"(cv.u[3]) : "v"(hi4[2]), "v"(hi4[3]));
#pragma unroll
    for (int r = 0; r < 2; ++r)
#pragma unroll
      for (int cg = 0; cg < 4; ++cg) {
        const s16x8 b = *(const s16x8*)&wfr[((r * 16 + ks2 * 4 + cg) * 64 + lane) * 8];
        acc[r][cg] = __builtin_amdgcn_mfma_f32_16x16x32_bf16(cv.v, b, acc[r][cg], 0, 0, 0);
      }
  }

  // scatter: D[row=(hi*4+q)][p=cg*16+llo] -> B1 frag layout via LDS bounce
  float* Tw = &T[w][0];
#pragma unroll
  for (int r = 0; r < 2; ++r) {
#pragma unroll
    for (int cg = 0; cg < 4; ++cg)
#pragma unroll
      for (int q = 0; q < 4; ++q)
        Tw[(hi * 4 + q) * 68 + cg * 16 + llo] = acc[r][cg][q];
    __builtin_amdgcn_s_waitcnt(0);  // drain lgkm: wave-internal LDS ordering
    if ((hi >> 1) == w) {
      const int mloc0 = 8 * hi - w * 16;
      const int ks = (r * ADJ_N + m0) >> 5;
#pragma unroll
      for (int cg = 0; cg < 4; ++cg) {
        union { unsigned u[4]; s16x8 v; } pk;
#pragma unroll
        for (int jj = 0; jj < 4; ++jj) {
          const float f0 = Tw[(mloc0 + 2 * jj) * 68 + cg * 16 + llo];
          const float f1 = Tw[(mloc0 + 2 * jj + 1) * 68 + cg * 16 + llo];
          asm("v_cvt_pk_bf16_f32 %0, %1, %2" : "=v"(pk.u[jj]) : "v"(f0), "v"(f1));
        }
        *(s16x8*)&Bsw1[((size_t)(ks * 4 + cg) * 64 + lane) * 8] = pk.v;
      }
    }
    __builtin_amdgcn_s_waitcnt(0);  // reads done before next r overwrites T
  }
}

// ---------------------------------------------------------------------------
// gemm2: partial1[split][n][c] = sum_{k in split} adj[n][k] * B1frag[k][c]
// Round-2 proven structure, REV K-walk (L3 reuse of gemm1's co-resident tail).
// ---------------------------------------------------------------------------
__global__ __launch_bounds__(256, 4) void gemm2_adj(
    const float* __restrict__ adj, const unsigned short* __restrict__ Bfr,
    float* __restrict__ outp) {
  constexpr int BN = 64, CGS = 4, BK = 64, KRANGE = 2048, NSTEP = 32;
  __shared__ __align__(16) unsigned short Bsb[2][2 * CGS * 512];  // 16 KB

  const int bx = blockIdx.x;
  const int mblk = bx >> 3;
  const int split = bx & 7;
  const int n0 = mblk * 64;
  const int k0 = split * KRANGE;
  const int r = k0 >> 13;
  const int m0k = k0 & (ADJ_N - 1);

  const int tid = threadIdx.x;
  const int w = tid >> 6;
  const int lane = tid & 63;
  const int lhi = lane >> 4, llo = lane & 15;
  const int rowa = n0 + w * 16 + llo;

  const float* __restrict__ adjw =
      adj + ((size_t)r << 26) + (size_t)rowa * ADJ_N + m0k + lhi * 8;

  f32x4 acc[CGS];
#pragma unroll
  for (int b = 0; b < CGS; ++b) acc[b] = (f32x4){0.f, 0.f, 0.f, 0.f};

  auto loadA = [&](int step, f32x4 (&dst)[4]) {
#pragma unroll
    for (int kc = 0; kc < 2; ++kc)
#pragma unroll
      for (int h = 0; h < 2; ++h)
        dst[kc * 2 + h] = *(const f32x4*)(adjw + step * BK + kc * 32 + h * 4);
  };

  auto stageB = [&](int buf, int step) {
    const int ksb = (k0 >> 5) + step * 2;
    const unsigned short* g = Bfr + (size_t)ksb * CGS * 512 + w * (CGS / 2) * 512 + lane * 8;
#pragma unroll
    for (int i = 0; i < CGS / 2; ++i) {
      __builtin_amdgcn_global_load_lds(
          (const __attribute__((address_space(1))) void*)(g + i * 512),
          (__attribute__((address_space(3))) void*)((char*)&Bsb[buf][0] +
                                                    (w * (CGS / 2) + i) * 1024),
          16, 0, 0);
    }
  };

  auto compute = [&](int buf, f32x4 (&cur)[4]) {
#pragma unroll
    for (int kc = 0; kc < 2; ++kc) {
      union { unsigned u[4]; s16x8 v; } cv;
      asm("v_cvt_pk_bf16_f32 %0, %1, %2" : "=v"(cv.u[0]) : "v"(cur[kc * 2][0]), "v"(cur[kc * 2][1]));
      asm("v_cvt_pk_bf16_f32 %0, %1, %2" : "=v"(cv.u[1]) : "v"(cur[kc * 2][2]), "v"(cur[kc * 2][3]));
      asm("v_cvt_pk_bf16_f32 %0, %1, %2" : "=v"(cv.u[2]) : "v"(cur[kc * 2 + 1][0]), "v"(cur[kc * 2 + 1][1]));
      asm("v_cvt_pk_bf16_f32 %0, %1, %2" : "=v"(cv.u[3]) : "v"(cur[kc * 2 + 1][2]), "v"(cur[kc * 2 + 1][3]));
#pragma unroll
      for (int fc = 0; fc < CGS; ++fc) {
        const s16x8 b = *(const s16x8*)((const char*)&Bsb[buf][0] +
                                        (((kc * CGS + fc) * 64 + lane) << 4));
        acc[fc] = __builtin_amdgcn_mfma_f32_16x16x32_bf16(cv.v, b, acc[fc], 0, 0, 0);
      }
    }
  };

  f32x4 a0[4], a1[4];
  loadA(NSTEP - 1, a0);
  stageB(0, NSTEP - 1);
  __syncthreads();

  for (int s2 = 0; s2 < NSTEP; s2 += 2) {
    stageB(1, NSTEP - 2 - s2);
    loadA(NSTEP - 2 - s2, a1);
    compute(0, a0);
    __syncthreads();
    if (s2 + 2 < NSTEP) {
      stageB(0, NSTEP - 3 - s2);
      loadA(NSTEP - 3 - s2, a0);
    }
    compute(1, a1);
    __syncthreads();
  }

  float* po = outp + ((size_t)split * ADJ_N + (size_t)n0) * BN;
#pragma unroll
  for (int fc = 0; fc < CGS; ++fc)
#pragma unroll
    for (int q = 0; q < 4; ++q)
      po[(size_t)(w * 16 + lhi * 4 + q) * BN + fc * 16 + llo] = acc[fc][q];
}

// ---------------------------------------------------------------------------
// reduce_out1: out1 = sum of 8 partials; colsum -> frep[128:192].
// 1024 blocks x 256 threads, 8 rows each (4 blocks/CU).
// ---------------------------------------------------------------------------
__global__ __launch_bounds__(256) void reduce_out1(
    const float* __restrict__ p1, float* __restrict__ out1,
    float* __restrict__ frep) {
  __shared__ float red[256];
  const int t = threadIdx.x;
  const int col = t & 63, rl = t >> 6;
  const int n0 = blockIdx.x * 8;
  float cs = 0.f;
#pragma unroll
  for (int rr = 0; rr < 2; ++rr) {
    const size_t idx = (size_t)(n0 + rl * 2 + rr) * 64 + col;
    float s = 0.f;
#pragma unroll
    for (int sp = 0; sp < 8; ++sp) s += p1[(size_t)sp * 524288 + idx];
    out1[idx] = s;
    cs += s;
  }
  red[t] = cs;
  __syncthreads();
  if (t < 64)
    atomicAdd(&frep[128 + t], red[t] + red[t + 64] + red[t + 128] + red[t + 192]);
}

// ---------------------------------------------------------------------------
extern "C" void kernel_launch(void* const* d_in, const int* in_sizes, int n_in,
                              void* d_out, int out_size, void* d_ws, size_t ws_size,
                              hipStream_t stream) {
  const float* adj = (const float*)d_in[0];
  const float* bw0 = (const float*)d_in[1];
  const float* bc0 = (const float*)d_in[2];
  const float* bw1 = (const float*)d_in[3];
  const float* bc1 = (const float*)d_in[4];
  float* out = (float*)d_out;
  float* frep = out + (size_t)8192 * 64;

  char* ws = (char*)d_ws;
  float* p0 = (float*)ws;                                      // 32 MB
  float* p1 = (float*)(ws + (32u << 20));                      // 16 MB
  unsigned short* B0 = (unsigned short*)(ws + (48u << 20));    // 4 MB
  unsigned short* B1 = (unsigned short*)(ws + (52u << 20));    // 2 MB
  float* h = (float*)(ws + (56u << 20));                       // 4 MB
  unsigned short* W1c = (unsigned short*)(ws + (60u << 20));   // 32 KB

  build_W1c<<<8, 256, 0, stream>>>(bw1, bc1, W1c, frep);
  build_B0<<<1024, 256, 0, stream>>>(bw0, bc0, B0);
  gemm1_adj<<<1024, 256, 0, stream>>>(adj, B0, p0);
  reduce_h<<<1024, 256, 0, stream>>>(p0, h, frep);
  build_B1_mfma<<<256, 128, 0, stream>>>(h, W1c, B1);
  gemm2_adj<<<1024, 256, 0, stream>>>(adj, B1, p1);
  reduce_out1<<<1024, 256, 0, stream>>>(p1, out, frep);
}